// Round 3
// baseline (314.574 us; speedup 1.0000x reference)
//
#include <hip/hip_runtime.h>
#include <math.h>

typedef _Float16 f16;
typedef _Float16 f16x8 __attribute__((ext_vector_type(8)));
typedef float f32x4 __attribute__((ext_vector_type(4)));

#define LSEQ 200
#define LT 13       // l-tiles of 16 (padded 208)
#define LKS 7       // k-steps over l padded to 224
#define WSTRIDE 224 // f16 per w_c row (448 B: k0/k2 2-way bank alias = free)
#define ISTRIDE 80  // f16 per i_c row (160 B: 2-way alias at worst)

// One block per sample n. 256 threads = 4 waves.
// LDS 31.6 KB + VGPR<=96 -> 5 blocks/CU (R2 was 39 KB -> 4).
// w/i stored as compact rows; MFMA A/B frags built per-lane at read (cc<3).
// softmax fused into delta phase: D-frag has all 3 capsule logits per lane.
__global__ __launch_bounds__(256, 4)
void capsule_kernel(const float* __restrict__ E,   // [N,200,64]
                    const float* __restrict__ W,   // [64,64]
                    const float* __restrict__ RL,  // [N,3,200]
                    const int* __restrict__ SL,    // [N]
                    float* __restrict__ out)       // [N,3,64]
{
    __shared__ f16 m_sw[LT*2*64*8];     // 26624 B: E frags -> mappings row-frag
    __shared__ f16 w_c[3*WSTRIDE];      //  1344 B: routing weights, compact rows
    __shared__ f16 i_c[3*ISTRIDE];      //   480 B: interests, compact rows
    __shared__ float logits[3*LSEQ];    //  2400 B
    __shared__ float cand[3*64];        //   768 B
    // total 31616 B -> 5 blocks/CU

    const int n = blockIdx.x;
    const int t = threadIdx.x;
    const int lane = t & 63;
    const int wv = t >> 6;
    const int q = lane >> 4;      // quad
    const int cc = lane & 15;     // column within MFMA tile

    // ---- W B-frags for this wave's o-tile, direct from global (16 KB, L2-hot)
    const int o_own = wv*16 + cc;
    f16x8 wB[2];
    #pragma unroll
    for (int ks = 0; ks < 2; ks++) {
        f16x8 h;
        #pragma unroll
        for (int j = 0; j < 8; j++) h[j] = (f16)W[(ks*32 + q*8 + j)*64 + o_own];
        wB[ks] = h;
    }

    const float4 f4z = make_float4(0.f, 0.f, 0.f, 0.f);

    // ---- stage E (fp32 -> f16, A-fragment-swizzled). Pad rows 200..207 = 0.
    const float* Eb = E + (size_t)n * (LSEQ*64);
    for (int g = t; g < LT*2*64; g += 256) {
        int sb = g >> 6, c = g & 63;
        int Tl = sb >> 1, ks = sb & 1;
        int qq = c >> 4, m = c & 15;
        int l = Tl*16 + m;
        int kb = ks*32 + qq*8;
        float4 v0 = f4z, v1 = f4z;
        if (l < LSEQ) {
            v0 = *(const float4*)(Eb + l*64 + kb);
            v1 = *(const float4*)(Eb + l*64 + kb + 4);
        }
        f16x8 h = { (f16)v0.x,(f16)v0.y,(f16)v0.z,(f16)v0.w,
                    (f16)v1.x,(f16)v1.y,(f16)v1.z,(f16)v1.w };
        *(f16x8*)&m_sw[g*8] = h;
    }

    // ---- stage logits (vectorized: 150 threads x float4 = 600 floats)
    if (t < 150) {
        float4 v = *(const float4*)(RL + (size_t)n * 600 + t*4);
        *(float4*)&logits[t*4] = v;
    }
    const int s = SL[n];

    __syncthreads();

    // ---- main matmul: mappings = E @ W. wave wv owns o-tile wv, 13 l-tiles.
    f32x4 acc[LT];
    #pragma unroll
    for (int Tl = 0; Tl < LT; Tl++) {
        f32x4 c0 = {0.f, 0.f, 0.f, 0.f};
        #pragma unroll
        for (int ks = 0; ks < 2; ks++) {
            f16x8 a = *(f16x8*)&m_sw[((Tl*2 + ks)*64 + lane)*8];
            c0 = __builtin_amdgcn_mfma_f32_16x16x32_f16(a, wB[ks], c0, 0, 0, 0);
        }
        acc[Tl] = c0;
    }
    __syncthreads();   // all E reads complete before overlay writes

    // ---- epilogue: D frag (row=q*4+r, col=cc) -> f16 row-frag m in m_sw
    const int kso = o_own >> 5, qo = (o_own & 31) >> 3, jo = o_own & 7;
    #pragma unroll
    for (int Tl = 0; Tl < LT; Tl++) {
        #pragma unroll
        for (int r = 0; r < 4; r++) {
            int lp = q*4 + r;
            m_sw[((Tl*2 + kso)*64 + qo*16 + lp)*8 + jo] = (f16)acc[Tl][r];
        }
    }
    __syncthreads();

    // ---- build cand A-frags in registers: A[m=o_own][kk=l]; l>=208 -> 0
    f16x8 mfrag[LKS];
    #pragma unroll
    for (int ks = 0; ks < LKS; ks++) {
        f16x8 h;
        #pragma unroll
        for (int j = 0; j < 8; j++) {
            int l = ks*32 + q*8 + j;
            f16 v = (f16)0.f;
            if (l < 208) {
                int Tl = l >> 4, lp = l & 15;
                v = m_sw[((Tl*2 + kso)*64 + qo*16 + lp)*8 + jo];
            }
            h[j] = v;
        }
        mfrag[ks] = h;
    }

    // ---- softmax over k for iteration 0 (initial logits)
    if (t < LSEQ) {
        float w0, w1, w2;
        if (t < s) {
            float l0 = logits[t], l1 = logits[LSEQ + t], l2 = logits[2*LSEQ + t];
            float mx = fmaxf(fmaxf(l0, l1), l2);
            float e0 = expf(l0 - mx), e1 = expf(l1 - mx), e2 = expf(l2 - mx);
            float inv = 1.f / (e0 + e1 + e2);
            w0 = e0*inv; w1 = e1*inv; w2 = e2*inv;
        } else {
            w0 = w1 = w2 = (1.f/3.f);
        }
        w_c[t]             = (f16)w0;
        w_c[WSTRIDE + t]   = (f16)w1;
        w_c[2*WSTRIDE + t] = (f16)w2;
    }
    __syncthreads();

    const f16x8 hz = {(f16)0.f,(f16)0.f,(f16)0.f,(f16)0.f,
                      (f16)0.f,(f16)0.f,(f16)0.f,(f16)0.f};

    // ---- routing: 3 iterations; delta+softmax fused at end of iters 0,1
    for (int iter = 0; iter < 3; iter++) {
        // cand^T[o][k] = sum_l m[l][o]*w[k][l]  (A=mfrag regs, B built from w_c)
        f32x4 ca = {0.f, 0.f, 0.f, 0.f};
        #pragma unroll
        for (int ks = 0; ks < LKS; ks++) {
            f16x8 b = hz;
            if (cc < 3) b = *(f16x8*)&w_c[cc*WSTRIDE + ks*32 + q*8];
            ca = __builtin_amdgcn_mfma_f32_16x16x32_f16(mfrag[ks], b, ca, 0, 0, 0);
        }
        // D[m=o][n=caps]: col=cc=capsule, row=q*4+r = o within tile
        if (cc < 3) {
            #pragma unroll
            for (int r = 0; r < 4; r++) cand[cc*64 + wv*16 + q*4 + r] = ca[r];
        }
        __syncthreads();

        // squash per capsule k (waves 0..2), write interests or final output
        if (t < 192) {
            float x = cand[t];
            float sq = x*x;
            #pragma unroll
            for (int off = 32; off >= 1; off >>= 1) sq += __shfl_xor(sq, off, 64);
            float factor = sq / ((1.f + sq) * sqrtf(sq + 1e-8f));
            float y = factor * x;
            if (iter < 2) {
                int k = t >> 6, o = t & 63;
                i_c[k*ISTRIDE + o] = (f16)y;
            } else {
                out[(size_t)n*192 + t] = y;
            }
        }
        if (iter == 2) break;
        __syncthreads();

        // delta: logits[k][l] += sum_o i[k][o]*m[l][o]; fused next-softmax.
        // D[m=k][n=l]: lanes 0..15 (q==0) hold rows k=0..2 for l=Tn*16+lane.
        for (int Tn = wv; Tn < LT; Tn += 4) {
            f32x4 da = {0.f, 0.f, 0.f, 0.f};
            #pragma unroll
            for (int ko = 0; ko < 2; ko++) {
                f16x8 a = hz;
                if (cc < 3) a = *(f16x8*)&i_c[cc*ISTRIDE + ko*32 + q*8];
                f16x8 b = *(f16x8*)&m_sw[((Tn*2 + ko)*64 + lane)*8];
                da = __builtin_amdgcn_mfma_f32_16x16x32_f16(a, b, da, 0, 0, 0);
            }
            if (lane < 16) {
                int l = Tn*16 + lane;
                if (l < LSEQ) {
                    float w0, w1, w2;
                    if (l < s) {
                        float l0 = logits[l]          + da[0];
                        float l1 = logits[LSEQ + l]   + da[1];
                        float l2 = logits[2*LSEQ + l] + da[2];
                        logits[l] = l0; logits[LSEQ + l] = l1; logits[2*LSEQ + l] = l2;
                        float mx = fmaxf(fmaxf(l0, l1), l2);
                        float e0 = expf(l0 - mx), e1 = expf(l1 - mx), e2 = expf(l2 - mx);
                        float inv = 1.f / (e0 + e1 + e2);
                        w0 = e0*inv; w1 = e1*inv; w2 = e2*inv;
                    } else {
                        w0 = w1 = w2 = (1.f/3.f);
                    }
                    w_c[l]             = (f16)w0;
                    w_c[WSTRIDE + l]   = (f16)w1;
                    w_c[2*WSTRIDE + l] = (f16)w2;
                }
            }
        }
        __syncthreads();
    }
}

extern "C" void kernel_launch(void* const* d_in, const int* in_sizes, int n_in,
                              void* d_out, int out_size, void* d_ws, size_t ws_size,
                              hipStream_t stream) {
    const float* E  = (const float*)d_in[0];
    const float* W  = (const float*)d_in[1];
    const float* RL = (const float*)d_in[2];
    const int*   SL = (const int*)d_in[3];
    float* o = (float*)d_out;
    const int N = in_sizes[3];   // seq_len has N entries
    capsule_kernel<<<dim3(N), dim3(256), 0, stream>>>(E, W, RL, SL, o);
}

// Round 4
// 302.499 us; speedup vs baseline: 1.0399x; 1.0399x over previous
//
#include <hip/hip_runtime.h>
#include <math.h>

typedef _Float16 f16;
typedef _Float16 f16x8 __attribute__((ext_vector_type(8)));
typedef float f32x4 __attribute__((ext_vector_type(4)));

#define LSEQ 200
#define LT 13       // l-tiles of 16 (padded 208; chunk space padded to 1792)

// One block per sample n. 256 threads = 4 waves.
// R4: uniform unrolled staging (no per-iter latency serialization), logits in
// registers (delta-owner lanes), softmax0 fused into epilogue, 10 barriers.
// LDS 31264 B -> 5 blocks/CU.
__global__ __launch_bounds__(256, 5)
void capsule_kernel(const float* __restrict__ E,   // [N,200,64]
                    const float* __restrict__ W,   // [64,64]
                    const float* __restrict__ RL,  // [N,3,200]
                    const int* __restrict__ SL,    // [N]
                    float* __restrict__ out)       // [N,3,64]
{
    __shared__ f16 m_sw[1792*8];     // 28672 B: E frags -> mappings row-frag (A-chunks)
    __shared__ f16 w_c[3*224];       //  1344 B: routing weights rows
    __shared__ f16 i_c[3*80];        //   480 B: interests rows
    __shared__ float cand[192];      //   768 B
    // total 31264 B -> 5 blocks/CU

    const int n = blockIdx.x;
    const int t = threadIdx.x;
    const int lane = t & 63;
    const int wv = t >> 6;
    const int q = lane >> 4;        // quad
    const int cc = lane & 15;       // column within MFMA tile
    const int cmin = cc < 3 ? cc : 2;

    // ---- W B-frags for this wave's o-tile, direct from global (L2-hot)
    const int o_own = wv*16 + cc;
    f16x8 wB[2];
    #pragma unroll
    for (int ks = 0; ks < 2; ks++) {
        f16x8 h;
        #pragma unroll
        for (int j = 0; j < 8; j++) h[j] = (f16)W[(ks*32 + q*8 + j)*64 + o_own];
        wB[ks] = h;
    }

    // ---- initial logits -> registers (owner: lane<16 of wave wv, Tn = wv+4*slot)
    float lg[4][3];
    #pragma unroll
    for (int slot = 0; slot < 4; slot++) {
        int Tn = wv + slot*4;
        if (Tn < LT && lane < 16) {
            int l = Tn*16 + lane;
            if (l < LSEQ) {
                lg[slot][0] = RL[(size_t)n*600 + l];
                lg[slot][1] = RL[(size_t)n*600 + 200 + l];
                lg[slot][2] = RL[(size_t)n*600 + 400 + l];
            }
        }
    }
    const int s = SL[n];

    // ---- zero w_c tail l in [200,224) (NaN-safety: garbage f16 could be Inf/NaN)
    if (t < 9) {
        const f16x8 hz = {(f16)0.f,(f16)0.f,(f16)0.f,(f16)0.f,
                          (f16)0.f,(f16)0.f,(f16)0.f,(f16)0.f};
        int row = t / 3, off = 200 + (t % 3)*8;
        *(f16x8*)&w_c[row*224 + off] = hz;
    }

    // ---- stage E (fp32 -> f16, A-fragment-swizzled), UNIFORM 7 iters, unrolled.
    //      chunks >= 1664 (l >= 208) write zeros into the pad region (harmless).
    const float* Eb = E + (size_t)n * (LSEQ*64);
    const float4 f4z = make_float4(0.f, 0.f, 0.f, 0.f);
    #pragma unroll
    for (int i = 0; i < 7; i++) {
        int g = t + i*256;               // 0..1791, uniform across threads
        int sb = g >> 6, c = g & 63;
        int Tl = sb >> 1, ks = sb & 1;
        int qq = c >> 4, m = c & 15;
        int l = Tl*16 + m;
        int kb = ks*32 + qq*8;
        float4 v0 = f4z, v1 = f4z;
        if (l < LSEQ) {
            v0 = *(const float4*)(Eb + l*64 + kb);
            v1 = *(const float4*)(Eb + l*64 + kb + 4);
        }
        f16x8 h = { (f16)v0.x,(f16)v0.y,(f16)v0.z,(f16)v0.w,
                    (f16)v1.x,(f16)v1.y,(f16)v1.z,(f16)v1.w };
        *(f16x8*)&m_sw[g*8] = h;
    }

    __syncthreads();   // B1

    // ---- main matmul: mappings = E @ W. wave wv owns o-tile wv, 13 l-tiles.
    f32x4 acc[LT];
    #pragma unroll
    for (int Tl = 0; Tl < LT; Tl++) {
        f32x4 c0 = {0.f, 0.f, 0.f, 0.f};
        #pragma unroll
        for (int ks = 0; ks < 2; ks++) {
            f16x8 a = *(f16x8*)&m_sw[((Tl*2 + ks)*64 + lane)*8];
            c0 = __builtin_amdgcn_mfma_f32_16x16x32_f16(a, wB[ks], c0, 0, 0, 0);
        }
        acc[Tl] = c0;
    }
    __syncthreads();   // B2: all E reads complete before overlay writes

    // ---- epilogue: D frag (row=q*4+r, col=cc) -> f16 A-chunk m in m_sw
    //      (rows l=200..207 are zero since E rows were zero -> writes zeros)
    const int kso = o_own >> 5, qo = (o_own & 31) >> 3, jo = o_own & 7;
    #pragma unroll
    for (int Tl = 0; Tl < LT; Tl++) {
        #pragma unroll
        for (int r = 0; r < 4; r++) {
            int lp = q*4 + r;
            m_sw[((Tl*2 + kso)*64 + qo*16 + lp)*8 + jo] = (f16)acc[Tl][r];
        }
    }
    // ---- fused softmax0 by logits owners -> w_c
    #pragma unroll
    for (int slot = 0; slot < 4; slot++) {
        int Tn = wv + slot*4;
        if (Tn < LT && lane < 16) {
            int l = Tn*16 + lane;
            if (l < LSEQ) {
                float w0, w1, w2;
                if (l < s) {
                    float l0 = lg[slot][0], l1 = lg[slot][1], l2 = lg[slot][2];
                    float mx = fmaxf(fmaxf(l0, l1), l2);
                    float e0 = expf(l0 - mx), e1 = expf(l1 - mx), e2 = expf(l2 - mx);
                    float inv = 1.f / (e0 + e1 + e2);
                    w0 = e0*inv; w1 = e1*inv; w2 = e2*inv;
                } else {
                    w0 = w1 = w2 = (1.f/3.f);
                }
                w_c[l]       = (f16)w0;
                w_c[224 + l] = (f16)w1;
                w_c[448 + l] = (f16)w2;
            }
        }
    }
    __syncthreads();   // B3

    // ---- build cand A-frags in registers: A[m=o_own][kk=l]; l>=208 -> 0
    f16x8 mfrag[7];
    #pragma unroll
    for (int ks = 0; ks < 7; ks++) {
        f16x8 h;
        #pragma unroll
        for (int j = 0; j < 8; j++) {
            int l = ks*32 + q*8 + j;
            f16 v = (f16)0.f;
            if (l < 208) {
                int Tl = l >> 4, lp = l & 15;
                v = m_sw[((Tl*2 + kso)*64 + qo*16 + lp)*8 + jo];
            }
            h[j] = v;
        }
        mfrag[ks] = h;
    }

    // ---- routing: 3 iterations; delta+softmax fused at end of iters 0,1
    for (int iter = 0; iter < 3; iter++) {
        // cand^T[o][k] = sum_l m[l][o]*w[k][l]  (A=mfrag regs, B=w_c rows)
        f32x4 ca = {0.f, 0.f, 0.f, 0.f};
        #pragma unroll
        for (int ks = 0; ks < 7; ks++) {
            f16x8 b = *(f16x8*)&w_c[cmin*224 + ks*32 + q*8];
            ca = __builtin_amdgcn_mfma_f32_16x16x32_f16(mfrag[ks], b, ca, 0, 0, 0);
        }
        // D[m=o][n=caps]: col=cc=capsule, row=q*4+r = o within tile
        if (cc < 3) {
            #pragma unroll
            for (int r = 0; r < 4; r++) cand[cc*64 + wv*16 + q*4 + r] = ca[r];
        }
        __syncthreads();

        // squash per capsule k (waves 0..2), write interests or final output
        if (t < 192) {
            float x = cand[t];
            float sq = x*x;
            #pragma unroll
            for (int off = 32; off >= 1; off >>= 1) sq += __shfl_xor(sq, off, 64);
            float factor = sq / ((1.f + sq) * sqrtf(sq + 1e-8f));
            float y = factor * x;
            if (iter < 2) {
                i_c[(t >> 6)*80 + (t & 63)] = (f16)y;
            } else {
                out[(size_t)n*192 + t] = y;
            }
        }
        if (iter == 2) break;
        __syncthreads();

        // delta: logits[k][l] += sum_o i[k][o]*m[l][o]; fused next-softmax.
        // D[m=k][n=l]: lanes 0..15 hold rows k=0..2 for l=Tn*16+lane.
        f16x8 ia[2];
        ia[0] = *(f16x8*)&i_c[cmin*80 + q*8];
        ia[1] = *(f16x8*)&i_c[cmin*80 + 32 + q*8];
        #pragma unroll
        for (int slot = 0; slot < 4; slot++) {
            int Tn = wv + slot*4;
            if (Tn < LT) {
                f32x4 da = {0.f, 0.f, 0.f, 0.f};
                #pragma unroll
                for (int ko = 0; ko < 2; ko++) {
                    f16x8 b = *(f16x8*)&m_sw[((Tn*2 + ko)*64 + lane)*8];
                    da = __builtin_amdgcn_mfma_f32_16x16x32_f16(ia[ko], b, da, 0, 0, 0);
                }
                if (lane < 16) {
                    int l = Tn*16 + lane;
                    if (l < LSEQ) {
                        float w0, w1, w2;
                        if (l < s) {
                            float l0 = lg[slot][0] + da[0];
                            float l1 = lg[slot][1] + da[1];
                            float l2 = lg[slot][2] + da[2];
                            lg[slot][0] = l0; lg[slot][1] = l1; lg[slot][2] = l2;
                            float mx = fmaxf(fmaxf(l0, l1), l2);
                            float e0 = expf(l0 - mx), e1 = expf(l1 - mx), e2 = expf(l2 - mx);
                            float inv = 1.f / (e0 + e1 + e2);
                            w0 = e0*inv; w1 = e1*inv; w2 = e2*inv;
                        } else {
                            w0 = w1 = w2 = (1.f/3.f);
                        }
                        w_c[l]       = (f16)w0;
                        w_c[224 + l] = (f16)w1;
                        w_c[448 + l] = (f16)w2;
                    }
                }
            }
        }
        __syncthreads();
    }
}

extern "C" void kernel_launch(void* const* d_in, const int* in_sizes, int n_in,
                              void* d_out, int out_size, void* d_ws, size_t ws_size,
                              hipStream_t stream) {
    const float* E  = (const float*)d_in[0];
    const float* W  = (const float*)d_in[1];
    const float* RL = (const float*)d_in[2];
    const int*   SL = (const int*)d_in[3];
    float* o = (float*)d_out;
    const int N = in_sizes[3];   // seq_len has N entries
    capsule_kernel<<<dim3(N), dim3(256), 0, stream>>>(E, W, RL, SL, o);
}